// Round 2
// 119.174 us; speedup vs baseline: 1.0333x; 1.0333x over previous
//
#include <hip/hip_runtime.h>

// Problem constants
#define NN 16       // batch
#define PB 16       // predicted masks
#define TB 8        // true masks
#define HWPX 50176  // 224*224
#define WORDS 784   // u64 words per plane (50176/64)
#define SGW 16      // words per supergroup (1024 px)
#define SGPP 49     // supergroups per plane (784/16)

typedef unsigned long long u64;
typedef u64 u64x2 __attribute__((ext_vector_type(2)));

// ---------------------------------------------------------------------------
// K1: bitpack both inputs + zero the small accumulators (block 0).
// Each wave-iteration: 4 independent float4 loads per lane (4 KiB/wave of
// coalesced reads), 16 ballots -> 16 u64 words, lane 0 stores 128 B
// contiguous. Pixel->bit mapping is a fixed permutation identical for pred
// and true planes, so popcount intersections and the permutation-invariant
// final mean are unaffected.
// ---------------------------------------------------------------------------
__global__ void pack_kernel(const float* __restrict__ pred,
                            const float* __restrict__ truth,
                            u64* __restrict__ PP, u64* __restrict__ PT,
                            float* __restrict__ inters, float* __restrict__ sp,
                            float* __restrict__ st, float* __restrict__ out) {
    // Fold K0 into block 0: zero accumulators before K2's atomics (safe:
    // K2 only starts after ALL pack blocks complete — stream order).
    if (blockIdx.x == 0) {
        const int TOT = NN * PB * TB + NN * PB + NN * TB + NN;  // 2448
        for (int i = threadIdx.x; i < TOT; i += blockDim.x) {
            if (i < NN * PB * TB) inters[i] = 0.f;
            else if (i < NN * PB * TB + NN * PB) sp[i - NN * PB * TB] = 0.f;
            else if (i < NN * PB * TB + NN * PB + NN * TB)
                st[i - NN * PB * TB - NN * PB] = 0.f;
            else out[i - NN * PB * TB - NN * PB - NN * TB] = 0.f;
        }
    }

    const int totalSG = (NN * PB + NN * TB) * SGPP;  // 18816
    const int wavesPerBlock = blockDim.x >> 6;
    const int waveId = blockIdx.x * wavesPerBlock + (threadIdx.x >> 6);
    const int lane = threadIdx.x & 63;
    const int nWaves = gridDim.x * wavesPerBlock;

    for (int G = waveId; G < totalSG; G += nWaves) {
        const int plane = G / SGPP;
        const int s = G - plane * SGPP;
        const float* src;
        u64* dst;
        if (plane < NN * PB) {
            src = pred + (size_t)plane * HWPX;
            dst = PP + (size_t)plane * WORDS;
        } else {
            const int q = plane - NN * PB;
            src = truth + (size_t)q * HWPX;
            dst = PT + (size_t)q * WORDS;
        }
        const float* b = src + s * 1024 + lane * 4;
        const float4 v0 = *(const float4*)(b);
        const float4 v1 = *(const float4*)(b + 256);
        const float4 v2 = *(const float4*)(b + 512);
        const float4 v3 = *(const float4*)(b + 768);
        u64 w0 = __ballot(v0.x != 0.f), w1 = __ballot(v0.y != 0.f);
        u64 w2 = __ballot(v0.z != 0.f), w3 = __ballot(v0.w != 0.f);
        u64 w4 = __ballot(v1.x != 0.f), w5 = __ballot(v1.y != 0.f);
        u64 w6 = __ballot(v1.z != 0.f), w7 = __ballot(v1.w != 0.f);
        u64 w8 = __ballot(v2.x != 0.f), w9 = __ballot(v2.y != 0.f);
        u64 wa = __ballot(v2.z != 0.f), wb = __ballot(v2.w != 0.f);
        u64 wc = __ballot(v3.x != 0.f), wd = __ballot(v3.y != 0.f);
        u64 we = __ballot(v3.z != 0.f), wf = __ballot(v3.w != 0.f);
        if (lane == 0) {
            u64x2* d = (u64x2*)(dst + s * SGW);  // 16B-aligned (s*128 bytes)
            u64x2 t0 = {w0, w1};
            u64x2 t1 = {w2, w3};
            u64x2 t2 = {w4, w5};
            u64x2 t3 = {w6, w7};
            u64x2 t4 = {w8, w9};
            u64x2 t5 = {wa, wb};
            u64x2 t6 = {wc, wd};
            u64x2 t7 = {we, wf};
            d[0] = t0;
            d[1] = t1;
            d[2] = t2;
            d[3] = t3;
            d[4] = t4;
            d[5] = t5;
            d[6] = t6;
            d[7] = t7;
        }
    }
}

// ---------------------------------------------------------------------------
// K2: inters[n,p,t] = popcount(PP[n,p] & PT[n,t]); also sp, st.
// grid = NN * K2_SPLIT blocks (896 -> ~7 waves/CU), 128 threads = one (p,t)
// pair each, 14 words per block via 7 ulonglong2 (16 B) loads per operand.
// ---------------------------------------------------------------------------
#define K2_SPLIT 56
#define K2_W (WORDS / K2_SPLIT)  // 14
__global__ void inters_kernel(const u64* __restrict__ PP,
                              const u64* __restrict__ PT,
                              float* __restrict__ inters,
                              float* __restrict__ sp, float* __restrict__ st) {
    const int n = blockIdx.x / K2_SPLIT;
    const int s = blockIdx.x % K2_SPLIT;
    const int p = threadIdx.x >> 3;
    const int t = threadIdx.x & 7;
    const u64* pp = PP + ((size_t)n * PB + p) * WORDS + s * K2_W;
    const u64* pt = PT + ((size_t)n * TB + t) * WORDS + s * K2_W;
    int acc = 0, accp = 0, acct = 0;
#pragma unroll
    for (int w = 0; w < K2_W; w += 2) {
        const u64x2 a = *(const u64x2*)(pp + w);  // base s*112B: 16B-aligned
        const u64x2 b = *(const u64x2*)(pt + w);
        acc += __popcll(a[0] & b[0]) + __popcll(a[1] & b[1]);
        accp += __popcll(a[0]) + __popcll(a[1]);
        acct += __popcll(b[0]) + __popcll(b[1]);
    }
    atomicAdd(&inters[((size_t)n * PB + p) * TB + t], (float)acc);
    if (t == 0) atomicAdd(&sp[n * PB + p], (float)accp);
    if (p == 0) atomicAdd(&st[n * TB + t], (float)acct);
}

// ---------------------------------------------------------------------------
// K3: per-block recompute iou_maxs[n,:] (cheap), hoist to registers, then
// per-pixel score from packed pred bits, block-reduce, one atomicAdd/block.
// grid = NN * 49 blocks (784 -> ~12 waves/CU), 256 threads; 16 words/block,
// each wave owns 4 contiguous words processed as 2 ulonglong2 word-pairs.
// ---------------------------------------------------------------------------
#define K3_CH 49
#define K3_W (WORDS / K3_CH)  // 16
__global__ void score_kernel(const u64* __restrict__ PP,
                             const float* __restrict__ inters,
                             const float* __restrict__ sp,
                             const float* __restrict__ st,
                             float* __restrict__ out) {
    const int n = blockIdx.x / K3_CH;
    const int c = blockIdx.x % K3_CH;
    __shared__ float ioumax_s[PB];
    __shared__ float redbuf[4];

    if (threadIdx.x < PB) {
        const int p = threadIdx.x;
        const float spv = sp[n * PB + p];
        float m = 0.f;
#pragma unroll
        for (int t = 0; t < TB; ++t) {
            const float iv = inters[((size_t)n * PB + p) * TB + t];
            const float un = spv + st[n * TB + t] - iv;
            const float iou = un > 0.f ? iv / un : 0.f;
            m = fmaxf(m, iou);
        }
        ioumax_s[p] = m;
    }
    __syncthreads();

    // hoist weights to registers (static unrolled indexing -> VGPRs)
    float wgt[PB];
#pragma unroll
    for (int p = 0; p < PB; ++p) wgt[p] = ioumax_s[p];

    const int lane = threadIdx.x & 63;
    const int wv = threadIdx.x >> 6;
    const int wbase = c * K3_W + wv * 4;  // 4 contiguous words per wave
    float sum = 0.f;
#pragma unroll
    for (int i = 0; i < 2; ++i) {
        const int w = wbase + i * 2;  // even word -> 16B-aligned
        float num0 = 0.f, den0 = 0.f, num1 = 0.f, den1 = 0.f;
#pragma unroll
        for (int p = 0; p < PB; ++p) {
            const u64x2 m = *(const u64x2*)(PP + ((size_t)n * PB + p) * WORDS + w);
            const float b0 = (float)(unsigned)((m[0] >> lane) & 1ull);
            const float b1 = (float)(unsigned)((m[1] >> lane) & 1ull);
            den0 += b0;
            num0 = fmaf(b0, wgt[p], num0);
            den1 += b1;
            num1 = fmaf(b1, wgt[p], num1);
        }
        sum += (den0 > 0.f ? num0 / den0 : 0.f) + (den1 > 0.f ? num1 / den1 : 0.f);
    }

    // wave reduce
#pragma unroll
    for (int off = 32; off > 0; off >>= 1) sum += __shfl_down(sum, off, 64);
    if (lane == 0) redbuf[wv] = sum;
    __syncthreads();
    if (threadIdx.x == 0) {
        const float tot = redbuf[0] + redbuf[1] + redbuf[2] + redbuf[3];
        atomicAdd(&out[n], tot * (1.0f / (float)HWPX));
    }
}

// ---------------------------------------------------------------------------
extern "C" void kernel_launch(void* const* d_in, const int* in_sizes, int n_in,
                              void* d_out, int out_size, void* d_ws, size_t ws_size,
                              hipStream_t stream) {
    const float* pred = (const float*)d_in[0];   // (N,P,H,W) fp32 {0,1}
    const float* truth = (const float*)d_in[1];  // (N,T,H,W) fp32 {0,1}
    float* out = (float*)d_out;                  // (N,)

    // workspace layout
    u64* PP = (u64*)d_ws;                              // 200704 u64
    u64* PT = PP + (size_t)NN * PB * WORDS;            // 100352 u64
    float* inters = (float*)(PT + (size_t)NN * TB * WORDS);  // 2048 f32
    float* sp = inters + NN * PB * TB;                 // 256 f32
    float* st = sp + NN * PB;                          // 128 f32

    pack_kernel<<<1176, 256, 0, stream>>>(pred, truth, PP, PT, inters, sp, st, out);
    inters_kernel<<<NN * K2_SPLIT, 128, 0, stream>>>(PP, PT, inters, sp, st);
    score_kernel<<<NN * K3_CH, 256, 0, stream>>>(PP, inters, sp, st, out);
}